// Round 8
// baseline (269.722 us; speedup 1.0000x reference)
//
#include <hip/hip_runtime.h>
#include <hip/hip_bf16.h>

// AAConv2d: B=8, CIN=128, H=W=32, COUT=128, K=3, DK=DV=64, NH=8, dkh=dvh=8
// out[:, 0:64]  = conv3x3(x, w_general) + b_general
// out[:, 64:128]= conv3x3(attn_combined, w_out) + b_out
// Rel logits (verified): logits[n,m] += dot(q[:, m>>5, n>>5], krw[(m&31)-(m>>5)+31])
//                                    + dot(q[:, m>>5, n>>5], krh[(n&31)-(n>>5)+31])
// dtype detected at runtime (fp32 in practice); compute fp32.
// R7 lesson: never mix s_load weights with ds_read in a hot loop (shared
// lgkmcnt, out-of-order returns => lgkmcnt(0) drains). All staged via LDS.

#define NP 1024
#define QSCALE 2.8284271247461903f   // q / (8^-0.5) = q*sqrt(8)
#define LOG2E  1.4426950408889634f

using bf16 = __hip_bfloat16;

__device__ __forceinline__ float b2f(bf16 v) { return __bfloat162float(v); }

__device__ __forceinline__ float dot8(const float* a, const float* b) {
  float s = a[0] * b[0];
  s = fmaf(a[1], b[1], s); s = fmaf(a[2], b[2], s); s = fmaf(a[3], b[3], s);
  s = fmaf(a[4], b[4], s); s = fmaf(a[5], b[5], s); s = fmaf(a[6], b[6], s);
  s = fmaf(a[7], b[7], s);
  return s;
}

__device__ __forceinline__ int fenc(float f) { int i = __float_as_int(f); return i < 0 ? (i ^ 0x7fffffff) : i; }
__device__ __forceinline__ float fdec(int i) { return __int_as_float(i < 0 ? (i ^ 0x7fffffff) : i); }

#if defined(__has_builtin)
#if __has_builtin(__builtin_amdgcn_exp2f)
#define EXP2F __builtin_amdgcn_exp2f
#else
#define EXP2F exp2f
#endif
#else
#define EXP2F exp2f
#endif

// ---------------------------------------------------------------------------
// Kernel 0: canonicalize all 9 inputs to fp32 in workspace; each block
// recomputes the dtype flag locally; block 0 publishes it for epilogues.
// ---------------------------------------------------------------------------
__global__ __launch_bounds__(256) void cvt_kernel(
    const void* __restrict__ p0, const void* __restrict__ p1, const void* __restrict__ p2,
    const void* __restrict__ p3, const void* __restrict__ p4, const void* __restrict__ p5,
    const void* __restrict__ p6, const void* __restrict__ p7, const void* __restrict__ p8,
    float* __restrict__ ws, int* __restrict__ flag)
{
  __shared__ int partial[4];
  int t = threadIdx.x;
  const unsigned* xraw = (const unsigned*)p0;
  int cnt = 0;
  for (int i = t; i < 1024; i += 256) {
    unsigned elo = (xraw[i] >> 7) & 0xffu;
    cnt += (elo >= 64u && elo <= 133u) ? 1 : 0;
  }
#pragma unroll
  for (int off = 1; off < 64; off <<= 1) cnt += __shfl_xor(cnt, off);
  if ((t & 63) == 0) partial[t >> 6] = cnt;
  __syncthreads();
  int tot = partial[0] + partial[1] + partial[2] + partial[3];
  int f32 = (tot >= 650) ? 0 : 1;   // 1 = fp32 tensors, 0 = bf16 tensors
  if (blockIdx.x == 0 && t == 0) *flag = f32;

  const void* src[9] = {p0, p1, p2, p3, p4, p5, p6, p7, p8};
  const int   n[9]    = {1048576, 73728, 64, 24576, 192, 36864, 64, 504, 504};
  const int   doff[9] = {0, 1048576, 1183744, 1122304, 1183808, 1146880, 1184000, 1184064, 1184568};
  int gsz = gridDim.x * 256;
  int gid = blockIdx.x * 256 + t;
#pragma unroll
  for (int s = 0; s < 9; s++) {
    float* dst = ws + doff[s];
    int ns = n[s];
    if (f32) {
      const float* sp = (const float*)src[s];
      for (int i = gid; i < ns; i += gsz) dst[i] = sp[i];
    } else {
      const bf16* sp = (const bf16*)src[s];
      for (int i = gid; i < ns; i += gsz) dst[i] = b2f(sp[i]);
    }
  }
}

// ---------------------------------------------------------------------------
// Kernel 1: qkv 1x1 conv (fp32). grid (b=8, pg=16, cog=6) = 768 blocks.
// Outer-product micro-tile: thread = 4 co x 2 px; per ci: b64(x)+b128(w)+8 FMA.
// All LDS (no SMEM mixing). LDS 50 KB -> 3 blocks/CU.
// ---------------------------------------------------------------------------
__global__ __launch_bounds__(256) void qkv_kernel(
    const float* __restrict__ xf, const float* __restrict__ wf, const float* __restrict__ bias,
    float* __restrict__ qbuf, float* __restrict__ kbuf, float* __restrict__ vbuf)
{
  __shared__ float xt[128][64];   // ci x px, 32 KB
  __shared__ float wt[128][36];   // ci x co (32 used, pad 36), 18 KB
  int b = blockIdx.x, pg = blockIdx.y, cog = blockIdx.z;
  int t = threadIdx.x;
  int p0 = pg * 64;
  const float* xs = xf + (size_t)b * 131072;
  for (int idx = t; idx < 8192; idx += 256) {
    int ci = idx >> 6, p = idx & 63;
    xt[ci][p] = xs[ci * 1024 + p0 + p];
  }
  for (int idx = t; idx < 4096; idx += 256) {
    int co = idx >> 7, ci = idx & 127;
    wt[ci][co] = wf[(cog * 32 + co) * 128 + ci];
  }
  __syncthreads();

  int cog2 = t >> 5;        // 0..7 -> 4 co each
  int pl = (t & 31) * 2;    // px pair
  float a0[4] = {0.f, 0.f, 0.f, 0.f};
  float a1[4] = {0.f, 0.f, 0.f, 0.f};
  for (int ci = 0; ci < 128; ci++) {
    float2 xv = *(const float2*)&xt[ci][pl];
    float4 wv = *(const float4*)&wt[ci][cog2 * 4];
    a0[0] = fmaf(xv.x, wv.x, a0[0]); a1[0] = fmaf(xv.y, wv.x, a1[0]);
    a0[1] = fmaf(xv.x, wv.y, a0[1]); a1[1] = fmaf(xv.y, wv.y, a1[1]);
    a0[2] = fmaf(xv.x, wv.z, a0[2]); a1[2] = fmaf(xv.y, wv.z, a1[2]);
    a0[3] = fmaf(xv.x, wv.w, a0[3]); a1[3] = fmaf(xv.y, wv.w, a1[3]);
  }
#pragma unroll
  for (int j = 0; j < 4; j++) {
    int co = cog * 32 + cog2 * 4 + j;
    float bv = bias[co];
    float v0 = a0[j] + bv, v1 = a1[j] + bv;
    float* dst;
    if (co < 64) { dst = qbuf; v0 *= QSCALE; v1 *= QSCALE; }
    else if (co < 128) dst = kbuf;
    else dst = vbuf;
    float2 pk; pk.x = v0; pk.y = v1;
    *(float2*)(dst + ((size_t)b * 64 + (co & 63)) * NP + p0 + pl) = pk;
  }
}

// ---------------------------------------------------------------------------
// Kernel 2: attention (unchanged from R7): single-pass upper-bound softmax,
// phase-split rows, K/V stream from global, ~22.5 KB LDS.
// ---------------------------------------------------------------------------
__global__ __launch_bounds__(256, 4) void attn_kernel(
    const float* __restrict__ qbuf, const float* __restrict__ kbuf, const float* __restrict__ vbuf,
    const float* __restrict__ krh, const float* __restrict__ krw,
    float* __restrict__ abuf)
{
  __shared__ float bw2[2][NP];         // 8 KB  (scaled by log2e)
  __shared__ float bhT[2][32][32];     // 8 KB  (scaled by log2e)
  __shared__ float qsT[2][32][8];      // 2 KB  (unscaled)
  __shared__ float krhs[64][8];        // 2 KB
  __shared__ float krws[64][8];        // 2 KB
  __shared__ int smax[3];

  int t = threadIdx.x;
  int cp = blockIdx.x, h = blockIdx.y, b = blockIdx.z;
  int C0 = cp * 2;
  const float* qbase = qbuf + ((size_t)b * 64 + h * 8) * NP;
  const float* kbase = kbuf + ((size_t)b * 64 + h * 8) * NP;
  const float* vbase = vbuf + ((size_t)b * 64 + h * 8) * NP;

  if (t < 3) smax[t] = (t == 0) ? 0 : fenc(-3.0e38f);

  for (int idx = t; idx < 63 * 8; idx += 256) {
    krhs[idx >> 3][idx & 7] = krh[idx];
    krws[idx >> 3][idx & 7] = krw[idx];
  }
  for (int idx = t; idx < 512; idx += 256) {
    int cs = idx >> 8, d = (idx >> 5) & 7, r = idx & 31;
    qsT[cs][r][d] = qbase[(size_t)d * NP + r * 32 + (C0 + cs)];
  }
  float kn2 = 0.f;
#pragma unroll
  for (int rr = 0; rr < 4; rr++) {
    int m = rr * 256 + t;
    const float4* ks = (const float4*)(kbase + (size_t)m * 8);
    float4 a = ks[0], c = ks[1];
    float nn = a.x * a.x + a.y * a.y + a.z * a.z + a.w * a.w +
               c.x * c.x + c.y * c.y + c.z * c.z + c.w * c.w;
    kn2 = fmaxf(kn2, nn);
  }
  __syncthreads();
  atomicMax(&smax[0], __float_as_int(kn2));

  float bwm = -3.0e38f;
  for (int idx = t; idx < 2048; idx += 256) {
    int cs = idx >> 10, m = idx & 1023;
    int rg = m >> 5, j2 = m & 31;
    float s = dot8(qsT[cs][rg], krws[j2 - rg + 31]) * LOG2E;
    bw2[cs][m] = s;
    bwm = fmaxf(bwm, s);
  }
  float bhm = -3.0e38f;
  for (int idx = t; idx < 2048; idx += 256) {
    int cs = idx >> 10, r = idx & 1023;
    int i = r >> 5, J = r & 31;
    float s = dot8(qsT[cs][i], krhs[J - (C0 + cs) + 31]) * LOG2E;
    bhT[cs][i][J] = s;
    bhm = fmaxf(bhm, s);
  }
  atomicMax(&smax[1], fenc(bwm));
  atomicMax(&smax[2], fenc(bhm));
  __syncthreads();

  float kmaxn = sqrtf(__int_as_float(smax[0]));
  float bmax = fdec(smax[1]) + fdec(smax[2]);

  int Csub = t >> 7, rowg = (t >> 5) & 3, seg = t & 31;
  int C = C0 + Csub;
  const float* bwX = bw2[Csub];
  const float* qrowbase = qbase + (size_t)C * 256 + rowg * 64;

#pragma unroll 1
  for (int ph = 0; ph < 2; ph++) {
    const float* qrow = qrowbase + ph * 32;
    float q[4][8], M[4], l[4], O[4][8];
#pragma unroll
    for (int r = 0; r < 4; r++) {
      float nn = 0.f;
#pragma unroll
      for (int d = 0; d < 8; d++) {
        float v = qrow[r * 8 + d] * LOG2E;
        q[r][d] = v;
        nn = fmaf(v, v, nn);
      }
      M[r] = sqrtf(nn) * kmaxn + bmax;
      l[r] = 0.f;
#pragma unroll
      for (int d = 0; d < 8; d++) O[r][d] = 0.f;
    }

    for (int i = 0; i < 32; ++i) {
      int m = i * 32 + seg;
      const float4* kp = (const float4*)(kbase + (size_t)m * 8);
      float4 ka = kp[0], kc = kp[1];
      float kk[8] = {ka.x, ka.y, ka.z, ka.w, kc.x, kc.y, kc.z, kc.w};
      const float4* vp = (const float4*)(vbase + (size_t)m * 8);
      float4 va = vp[0], vc = vp[1];
      float vv[8] = {va.x, va.y, va.z, va.w, vc.x, vc.y, vc.z, vc.w};
      float bwv = bwX[m];
      float4 bh4 = *(const float4*)&bhT[Csub][i][rowg * 8 + ph * 4];
      float cr[4] = {bh4.x, bh4.y, bh4.z, bh4.w};
#pragma unroll
      for (int r = 0; r < 4; ++r) {
        float s = bwv + (cr[r] - M[r]);
        s = fmaf(q[r][0], kk[0], s); s = fmaf(q[r][1], kk[1], s);
        s = fmaf(q[r][2], kk[2], s); s = fmaf(q[r][3], kk[3], s);
        s = fmaf(q[r][4], kk[4], s); s = fmaf(q[r][5], kk[5], s);
        s = fmaf(q[r][6], kk[6], s); s = fmaf(q[r][7], kk[7], s);
        float p = EXP2F(s);
        l[r] += p;
#pragma unroll
        for (int d = 0; d < 8; ++d) O[r][d] = fmaf(p, vv[d], O[r][d]);
      }
    }

#pragma unroll
    for (int off = 1; off < 32; off <<= 1) {
#pragma unroll
      for (int r = 0; r < 4; r++) {
        l[r] += __shfl_xor(l[r], off);
#pragma unroll
        for (int d = 0; d < 8; d++) O[r][d] += __shfl_xor(O[r][d], off);
      }
    }
    if (seg == 0) {
#pragma unroll
      for (int r = 0; r < 4; r++) {
        float inv = 1.f / l[r];
        int n = C * 32 + rowg * 8 + ph * 4 + r;
#pragma unroll
        for (int d = 0; d < 8; d++)
          abuf[((size_t)b * 64 + h * 8 + d) * NP + n] = O[r][d] * inv;
      }
    }
  }
}

// ---------------------------------------------------------------------------
// Kernel 3: direct 3x3 conv, pad 1, stride 1, Cout=64, H=W=32.
// grid (rg=8, coG=8, b=8) = 512 blocks. Tile: 8 co x 4 rows x 32 cols.
// Thread: 2 co x 2 px. x staged coalesced element-wise; weights staged in
// LDS (coalesced 144-float runs) and read via wave-uniform-address broadcast
// (cou = t>>6). Per ci: 6 b64(x) + 6(w, broadcast) + 36 FMA -> VALU-bound.
// ---------------------------------------------------------------------------
template <int CINT>
__global__ __launch_bounds__(256) void conv3x3_kernel(
    const float* __restrict__ in,    // [8][CINT][32][32]
    const float* __restrict__ wgt,   // [64][CINT][3][3]
    const float* __restrict__ bias,  // [64]
    void* __restrict__ out,          // [8][128][32][32] bf16 or fp32
    int co_base, const int* __restrict__ flag)
{
  __shared__ float xt[16][6][36];    // 13.5 KB: rows y0-1..y0+4, cols -1..34
  __shared__ float wt[16][8][12];    // 6 KB: [ci][co][k], 9 used, 48B rows
  int rg = blockIdx.x, coG = blockIdx.y, b = blockIdx.z;
  int y0 = rg * 4;
  int t = threadIdx.x;
  int cou = t >> 6;                  // 0..3 (wave-uniform), 2 co each
  int pxg = t & 63;
  int row = pxg >> 4, col = (pxg & 15) * 2;

  float acc[2][2] = {{0.f, 0.f}, {0.f, 0.f}};

  for (int ci0 = 0; ci0 < CINT; ci0 += 16) {
    __syncthreads();
    // coalesced element-wise x staging
    for (int s = t; s < 3456; s += 256) {
      int ci = s / 216, rem = s - ci * 216;
      int rr = rem / 36, cc = rem - rr * 36;
      int gy = y0 - 1 + rr, gx = cc - 1;
      float v = 0.f;
      if ((unsigned)gy < 32u && (unsigned)gx < 32u)
        v = in[((size_t)b * CINT + ci0 + ci) * 1024 + gy * 32 + gx];
      xt[ci][rr][cc] = v;
    }
    // weight staging: 8 co x 144-float contiguous runs
    for (int s = t; s < 1152; s += 256) {
      int co = s / 144, rem = s - co * 144;
      int ci = rem / 9, k = rem - ci * 9;
      wt[ci][co][k] = wgt[((size_t)(coG * 8 + co) * CINT + ci0) * 9 + rem];
    }
    __syncthreads();

    for (int ci = 0; ci < 16; ci++) {
      float xr[3][4];
#pragma unroll
      for (int ky = 0; ky < 3; ky++) {
        const float2* xp = (const float2*)&xt[ci][row + ky][col];
        float2 a = xp[0], c = xp[1];
        xr[ky][0] = a.x; xr[ky][1] = a.y; xr[ky][2] = c.x; xr[ky][3] = c.y;
      }
#pragma unroll
      for (int j = 0; j < 2; j++) {
        const float* wp = wt[ci][cou * 2 + j];   // wave-uniform addr: broadcast
        float4 wA = *(const float4*)wp;
        float4 wB = *(const float4*)(wp + 4);
        float w8 = wp[8];
        float wv[9] = {wA.x, wA.y, wA.z, wA.w, wB.x, wB.y, wB.z, wB.w, w8};
#pragma unroll
        for (int ky = 0; ky < 3; ky++)
#pragma unroll
          for (int kx = 0; kx < 3; kx++) {
            float w = wv[ky * 3 + kx];
            acc[j][0] = fmaf(xr[ky][kx], w, acc[j][0]);
            acc[j][1] = fmaf(xr[ky][kx + 1], w, acc[j][1]);
          }
      }
    }
  }

  int f32 = *flag;
  int yy = y0 + row;
#pragma unroll
  for (int j = 0; j < 2; j++) {
    int co = coG * 8 + cou * 2 + j;
    float bv = bias[co];
    float v0 = acc[j][0] + bv, v1 = acc[j][1] + bv;
    size_t eoff = ((size_t)b * 128 + co_base + co) * 1024 + yy * 32 + col;
    if (f32) {
      float* op = (float*)out + eoff;
      op[0] = v0; op[1] = v1;
    } else {
      bf16* op = (bf16*)out + eoff;
      op[0] = __float2bfloat16(v0);
      op[1] = __float2bfloat16(v1);
    }
  }
}

// ---------------------------------------------------------------------------
extern "C" void kernel_launch(void* const* d_in, const int* in_sizes, int n_in,
                              void* d_out, int out_size, void* d_ws, size_t ws_size,
                              hipStream_t stream) {
  float* ws    = (float*)d_ws;
  float* xf    = ws;                 // 1048576
  float* wgf   = ws + 1048576;       // 73728
  float* wqkvf = ws + 1122304;       // 24576
  float* wof   = ws + 1146880;       // 36864
  float* bgf   = ws + 1183744;       // 64
  float* bqkvf = ws + 1183808;       // 192
  float* bof   = ws + 1184000;       // 64
  float* krhf  = ws + 1184064;       // 504
  float* krwf  = ws + 1184568;       // 504
  float* qbuf  = ws + 1185280;       // 524288
  float* kbuf  = qbuf + 524288;
  float* vbuf  = kbuf + 524288;
  float* abuf  = vbuf + 524288;
  int*   flag  = (int*)(ws + 3282432);

  cvt_kernel<<<512, 256, 0, stream>>>(d_in[0], d_in[1], d_in[2], d_in[3], d_in[4],
                                      d_in[5], d_in[6], d_in[7], d_in[8], ws, flag);
  qkv_kernel<<<dim3(8, 16, 6), 256, 0, stream>>>(xf, wqkvf, bqkvf, qbuf, kbuf, vbuf);
  conv3x3_kernel<128><<<dim3(8, 8, 8), 256, 0, stream>>>(xf, wgf, bgf, d_out, 0, flag);
  attn_kernel<<<dim3(16, 8, 8), 256, 0, stream>>>(qbuf, kbuf, vbuf, krhf, krwf, abuf);
  conv3x3_kernel<64><<<dim3(8, 8, 8), 256, 0, stream>>>(abuf, wof, bof, d_out, 64, flag);
}

// Round 9
// 194.579 us; speedup vs baseline: 1.3862x; 1.3862x over previous
//
#include <hip/hip_runtime.h>
#include <hip/hip_bf16.h>

// AAConv2d: B=8, CIN=128, H=W=32, COUT=128, K=3, DK=DV=64, NH=8, dkh=dvh=8
// out[:, 0:64]  = conv3x3(x, w_general) + b_general
// out[:, 64:128]= conv3x3(attn_combined, w_out) + b_out
// Rel logits (verified): logits[n,m] += dot(q[:, m>>5, n>>5], krw[(m&31)-(m>>5)+31])
//                                    + dot(q[:, m>>5, n>>5], krh[(n&31)-(n>>5)+31])
// dtype detected at runtime (fp32 in practice); attention/qkv compute fp32;
// the two 3x3 convs run as bf16 MFMA implicit GEMM (9 shifted GEMMs
// accumulated; inputs pre-converted to channel-last zero-padded bf16).

#define NP 1024
#define QSCALE 2.8284271247461903f   // q / (8^-0.5) = q*sqrt(8)
#define LOG2E  1.4426950408889634f

using bf16 = __hip_bfloat16;
typedef unsigned short ushort;
typedef unsigned int uint;
using bf16x8 = __attribute__((ext_vector_type(8))) short;  // 8 bf16 = 4 VGPRs
using f32x4  = __attribute__((ext_vector_type(4))) float;

__device__ __forceinline__ float b2f(bf16 v) { return __bfloat162float(v); }
__device__ __forceinline__ ushort f2b(float v) {
  bf16 h = __float2bfloat16(v);
  ushort u; __builtin_memcpy(&u, &h, 2); return u;
}

__device__ __forceinline__ float dot8(const float* a, const float* b) {
  float s = a[0] * b[0];
  s = fmaf(a[1], b[1], s); s = fmaf(a[2], b[2], s); s = fmaf(a[3], b[3], s);
  s = fmaf(a[4], b[4], s); s = fmaf(a[5], b[5], s); s = fmaf(a[6], b[6], s);
  s = fmaf(a[7], b[7], s);
  return s;
}

__device__ __forceinline__ int fenc(float f) { int i = __float_as_int(f); return i < 0 ? (i ^ 0x7fffffff) : i; }
__device__ __forceinline__ float fdec(int i) { return __int_as_float(i < 0 ? (i ^ 0x7fffffff) : i); }

#if defined(__has_builtin)
#if __has_builtin(__builtin_amdgcn_exp2f)
#define EXP2F __builtin_amdgcn_exp2f
#else
#define EXP2F exp2f
#endif
#else
#define EXP2F exp2f
#endif

// ---- workspace float offsets ----------------------------------------------
#define OFF_XF     0
#define OFF_WQKV   1048576
#define OFF_BG     1073152
#define OFF_BQKV   1073216
#define OFF_BO     1073408
#define OFF_KRH    1073472
#define OFF_KRW    1073976
#define OFF_QBUF   1074496
#define OFF_KBUF   1598784
#define OFF_VBUF   2123072
#define OFF_XPB    2647360   // ushort[8*34*34*128] zero-padded channel-last x
#define OFF_APB    3239232   // ushort[8*34*34*64]  zero-padded channel-last attn
#define OFF_WGB    3535168   // ushort[9*64*128]    w_general [kykx][co][ci]
#define OFF_WOB    3572032   // ushort[9*64*64]     w_out     [kykx][co][ci]
#define OFF_FLAG   3590464

// ---------------------------------------------------------------------------
// Kernel 0: dtype detect + fp32 canonicalize + zero padded bf16 buffers +
// weight bf16 transforms ([co][ci][ky][kx] -> [kykx][co][ci]).
// ---------------------------------------------------------------------------
__global__ __launch_bounds__(256) void cvt_kernel(
    const void* __restrict__ p0, const void* __restrict__ p1, const void* __restrict__ p2,
    const void* __restrict__ p3, const void* __restrict__ p4, const void* __restrict__ p5,
    const void* __restrict__ p6, const void* __restrict__ p7, const void* __restrict__ p8,
    float* __restrict__ ws, int* __restrict__ flag)
{
  __shared__ int partial[4];
  int t = threadIdx.x;
  const unsigned* xraw = (const unsigned*)p0;
  int cnt = 0;
  for (int i = t; i < 1024; i += 256) {
    unsigned elo = (xraw[i] >> 7) & 0xffu;
    cnt += (elo >= 64u && elo <= 133u) ? 1 : 0;
  }
#pragma unroll
  for (int off = 1; off < 64; off <<= 1) cnt += __shfl_xor(cnt, off);
  if ((t & 63) == 0) partial[t >> 6] = cnt;
  __syncthreads();
  int tot = partial[0] + partial[1] + partial[2] + partial[3];
  int f32 = (tot >= 650) ? 0 : 1;   // 1 = fp32 tensors, 0 = bf16 tensors
  if (blockIdx.x == 0 && t == 0) *flag = f32;

  int gsz = gridDim.x * 256;
  int gid = blockIdx.x * 256 + t;

  // fp32 copies (x, wqkv, bg, bqkv, bo, krh, krw)
  const void* src[7] = {p0, p3, p2, p4, p6, p7, p8};
  const int   n[7]    = {1048576, 24576, 64, 192, 64, 504, 504};
  const int   doff[7] = {OFF_XF, OFF_WQKV, OFF_BG, OFF_BQKV, OFF_BO, OFF_KRH, OFF_KRW};
#pragma unroll
  for (int s = 0; s < 7; s++) {
    float* dst = ws + doff[s];
    int ns = n[s];
    if (f32) {
      const float* sp = (const float*)src[s];
      for (int i = gid; i < ns; i += gsz) dst[i] = sp[i];
    } else {
      const bf16* sp = (const bf16*)src[s];
      for (int i = gid; i < ns; i += gsz) dst[i] = b2f(sp[i]);
    }
  }

  // zero xpb + apb (contiguous region, 887808 floats)
  {
    float4* z = (float4*)(ws + OFF_XPB);
    for (int i = gid; i < 221952; i += gsz) z[i] = float4{0.f, 0.f, 0.f, 0.f};
  }

  // w_general -> wgb bf16 [kykx][co][ci]
  {
    ushort* wgb = (ushort*)(ws + OFF_WGB);
    for (int s = gid; s < 73728; s += gsz) {
      int kykx = s >> 13, co = (s >> 7) & 63, ci = s & 127;
      int si = (co * 128 + ci) * 9 + kykx;
      if (f32) wgb[s] = f2b(((const float*)p1)[si]);
      else { wgb[s] = ((const ushort*)p1)[si]; }
    }
  }
  // w_out -> wob bf16 [kykx][co][ci]
  {
    ushort* wob = (ushort*)(ws + OFF_WOB);
    for (int s = gid; s < 36864; s += gsz) {
      int kykx = s >> 12, co = (s >> 6) & 63, ci = s & 63;
      int si = (co * 64 + ci) * 9 + kykx;
      if (f32) wob[s] = f2b(((const float*)p5)[si]);
      else { wob[s] = ((const ushort*)p5)[si]; }
    }
  }
}

// ---------------------------------------------------------------------------
// Kernel 0b: x -> xpb bf16 channel-last zero-padded [8][34][34][128].
// One wave per 32 consecutive pixels; lane l handles ci {2l, 2l+1}; writes
// are one fully-coalesced 256B wave-store per pixel; reads stream 4B/lane
// sequentially over iterations (L1 line reuse).
// ---------------------------------------------------------------------------
__global__ __launch_bounds__(256) void xpose_kernel(
    const void* __restrict__ xin, ushort* __restrict__ xpb, const int* __restrict__ flag)
{
  int wglob = (blockIdx.x * 256 + threadIdx.x) >> 6;   // 0..255
  int lane = threadIdx.x & 63;
  int f32 = *flag;
  uint* xp32 = (uint*)xpb;
  for (int it = 0; it < 32; it++) {
    int p = wglob * 32 + it;
    int b = p >> 10, pp = p & 1023;
    int y = pp >> 5, x = pp & 31;
    uint u;
    if (f32) {
      const float* xs = (const float*)xin + ((size_t)b * 128 + 2 * lane) * 1024 + pp;
      u = (uint)f2b(xs[0]) | ((uint)f2b(xs[1024]) << 16);
    } else {
      const ushort* xs = (const ushort*)xin + ((size_t)b * 128 + 2 * lane) * 1024 + pp;
      u = (uint)xs[0] | ((uint)xs[1024] << 16);
    }
    xp32[((size_t)(b * 34 + y + 1) * 34 + x + 1) * 64 + lane] = u;
  }
}

// ---------------------------------------------------------------------------
// Kernel 1: qkv 1x1 conv (fp32). grid (b=8, pg=16, cog=6) = 768 blocks.
// ---------------------------------------------------------------------------
__global__ __launch_bounds__(256) void qkv_kernel(
    const float* __restrict__ xf, const float* __restrict__ wf, const float* __restrict__ bias,
    float* __restrict__ qbuf, float* __restrict__ kbuf, float* __restrict__ vbuf)
{
  __shared__ float xt[128][64];   // ci x px, 32 KB
  __shared__ float wt[128][36];   // ci x co (32 used, pad 36), 18 KB
  int b = blockIdx.x, pg = blockIdx.y, cog = blockIdx.z;
  int t = threadIdx.x;
  int p0 = pg * 64;
  const float* xs = xf + (size_t)b * 131072;
  for (int idx = t; idx < 8192; idx += 256) {
    int ci = idx >> 6, p = idx & 63;
    xt[ci][p] = xs[ci * 1024 + p0 + p];
  }
  for (int idx = t; idx < 4096; idx += 256) {
    int co = idx >> 7, ci = idx & 127;
    wt[ci][co] = wf[(cog * 32 + co) * 128 + ci];
  }
  __syncthreads();

  int cog2 = t >> 5;        // 0..7 -> 4 co each
  int pl = (t & 31) * 2;    // px pair
  float a0[4] = {0.f, 0.f, 0.f, 0.f};
  float a1[4] = {0.f, 0.f, 0.f, 0.f};
  for (int ci = 0; ci < 128; ci++) {
    float2 xv = *(const float2*)&xt[ci][pl];
    float4 wv = *(const float4*)&wt[ci][cog2 * 4];
    a0[0] = fmaf(xv.x, wv.x, a0[0]); a1[0] = fmaf(xv.y, wv.x, a1[0]);
    a0[1] = fmaf(xv.x, wv.y, a0[1]); a1[1] = fmaf(xv.y, wv.y, a1[1]);
    a0[2] = fmaf(xv.x, wv.z, a0[2]); a1[2] = fmaf(xv.y, wv.z, a1[2]);
    a0[3] = fmaf(xv.x, wv.w, a0[3]); a1[3] = fmaf(xv.y, wv.w, a1[3]);
  }
#pragma unroll
  for (int j = 0; j < 4; j++) {
    int co = cog * 32 + cog2 * 4 + j;
    float bv = bias[co];
    float v0 = a0[j] + bv, v1 = a1[j] + bv;
    float* dst;
    if (co < 64) { dst = qbuf; v0 *= QSCALE; v1 *= QSCALE; }
    else if (co < 128) dst = kbuf;
    else dst = vbuf;
    float2 pk; pk.x = v0; pk.y = v1;
    *(float2*)(dst + ((size_t)b * 64 + (co & 63)) * NP + p0 + pl) = pk;
  }
}

// ---------------------------------------------------------------------------
// Kernel 2: attention (structure unchanged from R7/R8); writeout goes
// directly to the padded channel-last bf16 buffer (8 ch = one dwordx4).
// ---------------------------------------------------------------------------
__global__ __launch_bounds__(256, 4) void attn_kernel(
    const float* __restrict__ qbuf, const float* __restrict__ kbuf, const float* __restrict__ vbuf,
    const float* __restrict__ krh, const float* __restrict__ krw,
    ushort* __restrict__ apb)
{
  __shared__ float bw2[2][NP];
  __shared__ float bhT[2][32][32];
  __shared__ float qsT[2][32][8];
  __shared__ float krhs[64][8];
  __shared__ float krws[64][8];
  __shared__ int smax[3];

  int t = threadIdx.x;
  int cp = blockIdx.x, h = blockIdx.y, b = blockIdx.z;
  int C0 = cp * 2;
  const float* qbase = qbuf + ((size_t)b * 64 + h * 8) * NP;
  const float* kbase = kbuf + ((size_t)b * 64 + h * 8) * NP;
  const float* vbase = vbuf + ((size_t)b * 64 + h * 8) * NP;

  if (t < 3) smax[t] = (t == 0) ? 0 : fenc(-3.0e38f);

  for (int idx = t; idx < 63 * 8; idx += 256) {
    krhs[idx >> 3][idx & 7] = krh[idx];
    krws[idx >> 3][idx & 7] = krw[idx];
  }
  for (int idx = t; idx < 512; idx += 256) {
    int cs = idx >> 8, d = (idx >> 5) & 7, r = idx & 31;
    qsT[cs][r][d] = qbase[(size_t)d * NP + r * 32 + (C0 + cs)];
  }
  float kn2 = 0.f;
#pragma unroll
  for (int rr = 0; rr < 4; rr++) {
    int m = rr * 256 + t;
    const float4* ks = (const float4*)(kbase + (size_t)m * 8);
    float4 a = ks[0], c = ks[1];
    float nn = a.x * a.x + a.y * a.y + a.z * a.z + a.w * a.w +
               c.x * c.x + c.y * c.y + c.z * c.z + c.w * c.w;
    kn2 = fmaxf(kn2, nn);
  }
  __syncthreads();
  atomicMax(&smax[0], __float_as_int(kn2));

  float bwm = -3.0e38f;
  for (int idx = t; idx < 2048; idx += 256) {
    int cs = idx >> 10, m = idx & 1023;
    int rg = m >> 5, j2 = m & 31;
    float s = dot8(qsT[cs][rg], krws[j2 - rg + 31]) * LOG2E;
    bw2[cs][m] = s;
    bwm = fmaxf(bwm, s);
  }
  float bhm = -3.0e38f;
  for (int idx = t; idx < 2048; idx += 256) {
    int cs = idx >> 10, r = idx & 1023;
    int i = r >> 5, J = r & 31;
    float s = dot8(qsT[cs][i], krhs[J - (C0 + cs) + 31]) * LOG2E;
    bhT[cs][i][J] = s;
    bhm = fmaxf(bhm, s);
  }
  atomicMax(&smax[1], fenc(bwm));
  atomicMax(&smax[2], fenc(bhm));
  __syncthreads();

  float kmaxn = sqrtf(__int_as_float(smax[0]));
  float bmax = fdec(smax[1]) + fdec(smax[2]);

  int Csub = t >> 7, rowg = (t >> 5) & 3, seg = t & 31;
  int C = C0 + Csub;
  const float* bwX = bw2[Csub];
  const float* qrowbase = qbase + (size_t)C * 256 + rowg * 64;

#pragma unroll 1
  for (int ph = 0; ph < 2; ph++) {
    const float* qrow = qrowbase + ph * 32;
    float q[4][8], M[4], l[4], O[4][8];
#pragma unroll
    for (int r = 0; r < 4; r++) {
      float nn = 0.f;
#pragma unroll
      for (int d = 0; d < 8; d++) {
        float v = qrow[r * 8 + d] * LOG2E;
        q[r][d] = v;
        nn = fmaf(v, v, nn);
      }
      M[r] = sqrtf(nn) * kmaxn + bmax;
      l[r] = 0.f;
#pragma unroll
      for (int d = 0; d < 8; d++) O[r][d] = 0.f;
    }

    for (int i = 0; i < 32; ++i) {
      int m = i * 32 + seg;
      const float4* kp = (const float4*)(kbase + (size_t)m * 8);
      float4 ka = kp[0], kc = kp[1];
      float kk[8] = {ka.x, ka.y, ka.z, ka.w, kc.x, kc.y, kc.z, kc.w};
      const float4* vp = (const float4*)(vbase + (size_t)m * 8);
      float4 va = vp[0], vc = vp[1];
      float vv[8] = {va.x, va.y, va.z, va.w, vc.x, vc.y, vc.z, vc.w};
      float bwv = bwX[m];
      float4 bh4 = *(const float4*)&bhT[Csub][i][rowg * 8 + ph * 4];
      float cr[4] = {bh4.x, bh4.y, bh4.z, bh4.w};
#pragma unroll
      for (int r = 0; r < 4; ++r) {
        float s = bwv + (cr[r] - M[r]);
        s = fmaf(q[r][0], kk[0], s); s = fmaf(q[r][1], kk[1], s);
        s = fmaf(q[r][2], kk[2], s); s = fmaf(q[r][3], kk[3], s);
        s = fmaf(q[r][4], kk[4], s); s = fmaf(q[r][5], kk[5], s);
        s = fmaf(q[r][6], kk[6], s); s = fmaf(q[r][7], kk[7], s);
        float p = EXP2F(s);
        l[r] += p;
#pragma unroll
        for (int d = 0; d < 8; ++d) O[r][d] = fmaf(p, vv[d], O[r][d]);
      }
    }

#pragma unroll
    for (int off = 1; off < 32; off <<= 1) {
#pragma unroll
      for (int r = 0; r < 4; r++) {
        l[r] += __shfl_xor(l[r], off);
#pragma unroll
        for (int d = 0; d < 8; d++) O[r][d] += __shfl_xor(O[r][d], off);
      }
    }
    if (seg == 0) {
#pragma unroll
      for (int r = 0; r < 4; r++) {
        float inv = 1.f / l[r];
        int n = C * 32 + rowg * 8 + ph * 4 + r;
        int yy = (n >> 5) + 1, xx = (n & 31) + 1;
        ushort u[8];
#pragma unroll
        for (int d = 0; d < 8; d++) u[d] = f2b(O[r][d] * inv);
        uint4 pk;
        pk.x = (uint)u[0] | ((uint)u[1] << 16);
        pk.y = (uint)u[2] | ((uint)u[3] << 16);
        pk.z = (uint)u[4] | ((uint)u[5] << 16);
        pk.w = (uint)u[6] | ((uint)u[7] << 16);
        *(uint4*)(apb + ((size_t)(b * 34 + yy) * 34 + xx) * 64 + h * 8) = pk;
      }
    }
  }
}

// ---------------------------------------------------------------------------
// Kernel 3: conv3x3 as bf16 MFMA implicit GEMM. Zero LDS; A/B fragments are
// direct dwordx4 global loads (L2-resident). Per wave: tile 16co x 16px,
// K = CINT*9 via 9 shifted GEMMs (ky,kx) x CINT/32 chunks, one acc chain.
// grid (pxtile=64, b=8) = 512 blocks, 256 thr = 4 waves (co groups of 16).
// xp: [8][34][34][CINT] bf16 (zero-padded); wp: [9][64][CINT] bf16.
// ---------------------------------------------------------------------------
template <int CINT>
__global__ __launch_bounds__(256) void conv_mfma_kernel(
    const ushort* __restrict__ xp, const ushort* __restrict__ wp,
    const float* __restrict__ bias, void* __restrict__ out,
    int co_base, const int* __restrict__ flag)
{
  int pt = blockIdx.x;            // px tile: 16 px
  int b  = blockIdx.y;
  int lane = threadIdx.x & 63;
  int w = threadIdx.x >> 6;       // wave -> co group (16 co)
  int n = lane & 15;              // A: m (co); B: n (px); shared index
  int kg = lane >> 4;             // k-group (8 ci each)
  int p0 = pt * 16;
  int y = p0 >> 5, x0 = p0 & 31;

  const ushort* abase = wp + (size_t)(w * 16 + n) * CINT + kg * 8;
  const ushort* bbase = xp + ((size_t)(b * 34 + y) * 34 + x0 + n) * CINT + kg * 8;

  f32x4 acc = {0.f, 0.f, 0.f, 0.f};
#pragma unroll
  for (int c = 0; c < CINT / 32; c++) {
    int ci0 = c * 32;
#pragma unroll
    for (int ky = 0; ky < 3; ky++) {
#pragma unroll
      for (int kx = 0; kx < 3; kx++) {
        bf16x8 A = *(const bf16x8*)(abase + (size_t)(ky * 3 + kx) * 64 * CINT + ci0);
        bf16x8 B = *(const bf16x8*)(bbase + (size_t)(ky * 34 + kx) * CINT + ci0);
        acc = __builtin_amdgcn_mfma_f32_16x16x32_bf16(A, B, acc, 0, 0, 0);
      }
    }
  }

  int f32o = *flag;
#pragma unroll
  for (int r = 0; r < 4; r++) {
    int co = w * 16 + kg * 4 + r;        // D row = (lane>>4)*4 + r
    float v = acc[r] + bias[co];
    size_t eoff = ((size_t)b * 128 + co_base + co) * 1024 + p0 + n;   // D col = n
    if (f32o) ((float*)out)[eoff] = v;
    else ((bf16*)out)[eoff] = __float2bfloat16(v);
  }
}

// ---------------------------------------------------------------------------
extern "C" void kernel_launch(void* const* d_in, const int* in_sizes, int n_in,
                              void* d_out, int out_size, void* d_ws, size_t ws_size,
                              hipStream_t stream) {
  float* ws = (float*)d_ws;
  float*  xf    = ws + OFF_XF;
  float*  wqkvf = ws + OFF_WQKV;
  float*  bgf   = ws + OFF_BG;
  float*  bqkvf = ws + OFF_BQKV;
  float*  bof   = ws + OFF_BO;
  float*  krhf  = ws + OFF_KRH;
  float*  krwf  = ws + OFF_KRW;
  float*  qbuf  = ws + OFF_QBUF;
  float*  kbuf  = ws + OFF_KBUF;
  float*  vbuf  = ws + OFF_VBUF;
  ushort* xpb   = (ushort*)(ws + OFF_XPB);
  ushort* apb   = (ushort*)(ws + OFF_APB);
  ushort* wgb   = (ushort*)(ws + OFF_WGB);
  ushort* wob   = (ushort*)(ws + OFF_WOB);
  int*    flag  = (int*)(ws + OFF_FLAG);

  cvt_kernel<<<512, 256, 0, stream>>>(d_in[0], d_in[1], d_in[2], d_in[3], d_in[4],
                                      d_in[5], d_in[6], d_in[7], d_in[8], ws, flag);
  xpose_kernel<<<64, 256, 0, stream>>>(d_in[0], xpb, flag);
  qkv_kernel<<<dim3(8, 16, 6), 256, 0, stream>>>(xf, wqkvf, bqkvf, qbuf, kbuf, vbuf);
  conv_mfma_kernel<128><<<dim3(64, 8), 256, 0, stream>>>(xpb, wgb, bgf, d_out, 0, flag);
  attn_kernel<<<dim3(16, 8, 8), 256, 0, stream>>>(qbuf, kbuf, vbuf, krhf, krwf, apb);
  conv_mfma_kernel<64><<<dim3(64, 8), 256, 0, stream>>>(apb, wob, bof, d_out, 64, flag);
}

// Round 10
// 185.892 us; speedup vs baseline: 1.4510x; 1.0467x over previous
//
#include <hip/hip_runtime.h>
#include <hip/hip_bf16.h>

// AAConv2d: B=8, CIN=128, H=W=32, COUT=128, K=3, DK=DV=64, NH=8, dkh=dvh=8
// out[:, 0:64]  = conv3x3(x, w_general) + b_general
// out[:, 64:128]= conv3x3(attn_combined, w_out) + b_out
// Rel logits (verified): logits[n,m] += dot(q[:, m>>5, n>>5], krw[(m&31)-(m>>5)+31])
//                                    + dot(q[:, m>>5, n>>5], krh[(n&31)-(n>>5)+31])
// dtype detected at runtime (fp32 in practice); attention/qkv compute fp32;
// 3x3 convs are bf16 MFMA implicit GEMM on channel-last zero-padded buffers.

#define NP 1024
#define QSCALE 2.8284271247461903f   // q / (8^-0.5) = q*sqrt(8)
#define LOG2E  1.4426950408889634f

using bf16 = __hip_bfloat16;
typedef unsigned short ushort;
typedef unsigned int uint;
using bf16x8 = __attribute__((ext_vector_type(8))) short;  // 8 bf16 = 4 VGPRs
using f32x4  = __attribute__((ext_vector_type(4))) float;

__device__ __forceinline__ float b2f(bf16 v) { return __bfloat162float(v); }
__device__ __forceinline__ ushort f2b(float v) {
  bf16 h = __float2bfloat16(v);
  ushort u; __builtin_memcpy(&u, &h, 2); return u;
}

__device__ __forceinline__ float dot8(const float* a, const float* b) {
  float s = a[0] * b[0];
  s = fmaf(a[1], b[1], s); s = fmaf(a[2], b[2], s); s = fmaf(a[3], b[3], s);
  s = fmaf(a[4], b[4], s); s = fmaf(a[5], b[5], s); s = fmaf(a[6], b[6], s);
  s = fmaf(a[7], b[7], s);
  return s;
}

__device__ __forceinline__ int fenc(float f) { int i = __float_as_int(f); return i < 0 ? (i ^ 0x7fffffff) : i; }
__device__ __forceinline__ float fdec(int i) { return __int_as_float(i < 0 ? (i ^ 0x7fffffff) : i); }

#if defined(__has_builtin)
#if __has_builtin(__builtin_amdgcn_exp2f)
#define EXP2F __builtin_amdgcn_exp2f
#else
#define EXP2F exp2f
#endif
#else
#define EXP2F exp2f
#endif

// ---- workspace float offsets ----------------------------------------------
#define OFF_WQKV   1048576
#define OFF_BG     1073152
#define OFF_BQKV   1073216
#define OFF_BO     1073408
#define OFF_KRH    1073472
#define OFF_KRW    1073976
#define OFF_QBUF   1074496
#define OFF_KBUF   1598784
#define OFF_VBUF   2123072
#define OFF_XPB    2647360   // ushort[8*34*34*128] zero-padded channel-last x
#define OFF_APB    3239232   // ushort[8*34*34*64]  zero-padded channel-last attn
#define OFF_WGB    3535168   // ushort[9*64*128]    w_general [kykx][co][ci]
#define OFF_WOB    3572032   // ushort[9*64*64]     w_out     [kykx][co][ci]
#define OFF_FLAG   3590464

// ---------------------------------------------------------------------------
// Kernel 0: dtype detect + small fp32 copies + zero padded bf16 buffers +
// weight bf16 transforms. (x is consumed raw by qkv/xpose now.)
// ---------------------------------------------------------------------------
__global__ __launch_bounds__(256) void cvt_kernel(
    const void* __restrict__ p0, const void* __restrict__ p1, const void* __restrict__ p2,
    const void* __restrict__ p3, const void* __restrict__ p4, const void* __restrict__ p5,
    const void* __restrict__ p6, const void* __restrict__ p7, const void* __restrict__ p8,
    float* __restrict__ ws, int* __restrict__ flag)
{
  __shared__ int partial[4];
  int t = threadIdx.x;
  const unsigned* xraw = (const unsigned*)p0;
  int cnt = 0;
  for (int i = t; i < 1024; i += 256) {
    unsigned elo = (xraw[i] >> 7) & 0xffu;
    cnt += (elo >= 64u && elo <= 133u) ? 1 : 0;
  }
#pragma unroll
  for (int off = 1; off < 64; off <<= 1) cnt += __shfl_xor(cnt, off);
  if ((t & 63) == 0) partial[t >> 6] = cnt;
  __syncthreads();
  int tot = partial[0] + partial[1] + partial[2] + partial[3];
  int f32 = (tot >= 650) ? 0 : 1;   // 1 = fp32 tensors, 0 = bf16 tensors
  if (blockIdx.x == 0 && t == 0) *flag = f32;

  int gsz = gridDim.x * 256;
  int gid = blockIdx.x * 256 + t;

  // fp32 copies (wqkv, bg, bqkv, bo, krh, krw)
  const void* src[6] = {p3, p2, p4, p6, p7, p8};
  const int   n[6]    = {24576, 64, 192, 64, 504, 504};
  const int   doff[6] = {OFF_WQKV, OFF_BG, OFF_BQKV, OFF_BO, OFF_KRH, OFF_KRW};
#pragma unroll
  for (int s = 0; s < 6; s++) {
    float* dst = ws + doff[s];
    int ns = n[s];
    if (f32) {
      const float* sp = (const float*)src[s];
      for (int i = gid; i < ns; i += gsz) dst[i] = sp[i];
    } else {
      const bf16* sp = (const bf16*)src[s];
      for (int i = gid; i < ns; i += gsz) dst[i] = b2f(sp[i]);
    }
  }

  // zero xpb + apb (contiguous region, 887808 floats = 221952 float4)
  {
    float4* z = (float4*)(ws + OFF_XPB);
    for (int i = gid; i < 221952; i += gsz) z[i] = float4{0.f, 0.f, 0.f, 0.f};
  }

  // w_general -> wgb bf16 [kykx][co][ci]
  {
    ushort* wgb = (ushort*)(ws + OFF_WGB);
    for (int s = gid; s < 73728; s += gsz) {
      int kykx = s >> 13, co = (s >> 7) & 63, ci = s & 127;
      int si = (co * 128 + ci) * 9 + kykx;
      if (f32) wgb[s] = f2b(((const float*)p1)[si]);
      else { wgb[s] = ((const ushort*)p1)[si]; }
    }
  }
  // w_out -> wob bf16 [kykx][co][ci]
  {
    ushort* wob = (ushort*)(ws + OFF_WOB);
    for (int s = gid; s < 36864; s += gsz) {
      int kykx = s >> 12, co = (s >> 6) & 63, ci = s & 63;
      int si = (co * 64 + ci) * 9 + kykx;
      if (f32) wob[s] = f2b(((const float*)p5)[si]);
      else { wob[s] = ((const ushort*)p5)[si]; }
    }
  }
}

// ---------------------------------------------------------------------------
// Kernel 0b: x -> xpb bf16 channel-last zero-padded [8][34][34][128].
// LDS tile transpose: coalesced reads (lane = pixel), conflict-free LDS
// (65-uint padded rows), coalesced 256B-per-pixel writes (lane = ci-pair).
// grid 128 blocks x 256 thr; block = 64 pixels x 128 ci.
// ---------------------------------------------------------------------------
__global__ __launch_bounds__(256) void xpose_kernel(
    const void* __restrict__ xin, ushort* __restrict__ xpb, const int* __restrict__ flag)
{
  __shared__ uint lds[64][65];   // [ci-pair][px], padded
  int t = threadIdx.x;
  int w = t >> 6, lane = t & 63;
  int bi = blockIdx.x;
  int b = bi >> 4;                  // batch
  int pp0 = (bi & 15) * 64;         // 64 consecutive pixels
  int f32 = *flag;

  if (f32) {
    const float* xs = (const float*)xin + (size_t)b * 131072 + pp0;
#pragma unroll 4
    for (int i = 0; i < 16; i++) {
      int cp = w * 16 + i;
      float v0 = xs[(size_t)(2 * cp) * 1024 + lane];
      float v1 = xs[(size_t)(2 * cp + 1) * 1024 + lane];
      lds[cp][lane] = (uint)f2b(v0) | ((uint)f2b(v1) << 16);
    }
  } else {
    const ushort* xs = (const ushort*)xin + (size_t)b * 131072 + pp0;
#pragma unroll 4
    for (int i = 0; i < 16; i++) {
      int cp = w * 16 + i;
      uint v0 = xs[(size_t)(2 * cp) * 1024 + lane];
      uint v1 = xs[(size_t)(2 * cp + 1) * 1024 + lane];
      lds[cp][lane] = v0 | (v1 << 16);
    }
  }
  __syncthreads();

  uint* xp32 = (uint*)xpb;
#pragma unroll 4
  for (int i = 0; i < 16; i++) {
    int p = w * 16 + i;
    int pp = pp0 + p;
    int y = pp >> 5, x = pp & 31;
    xp32[((size_t)(b * 34 + y + 1) * 34 + x + 1) * 64 + lane] = lds[lane][p];
  }
}

// ---------------------------------------------------------------------------
// Kernel 1: qkv 1x1 conv (fp32 accumulate; stages raw x with dtype branch).
// grid (b=8, pg=16, cog=6) = 768 blocks.
// ---------------------------------------------------------------------------
__global__ __launch_bounds__(256) void qkv_kernel(
    const void* __restrict__ xin, const float* __restrict__ wf, const float* __restrict__ bias,
    float* __restrict__ qbuf, float* __restrict__ kbuf, float* __restrict__ vbuf,
    const int* __restrict__ flag)
{
  __shared__ float xt[128][64];   // ci x px, 32 KB
  __shared__ float wt[128][36];   // ci x co (32 used, pad 36), 18 KB
  int b = blockIdx.x, pg = blockIdx.y, cog = blockIdx.z;
  int t = threadIdx.x;
  int p0 = pg * 64;
  int f32 = *flag;
  if (f32) {
    const float* xs = (const float*)xin + (size_t)b * 131072;
    for (int idx = t; idx < 8192; idx += 256) {
      int ci = idx >> 6, p = idx & 63;
      xt[ci][p] = xs[ci * 1024 + p0 + p];
    }
  } else {
    const bf16* xs = (const bf16*)xin + (size_t)b * 131072;
    for (int idx = t; idx < 8192; idx += 256) {
      int ci = idx >> 6, p = idx & 63;
      xt[ci][p] = b2f(xs[ci * 1024 + p0 + p]);
    }
  }
  for (int idx = t; idx < 4096; idx += 256) {
    int co = idx >> 7, ci = idx & 127;
    wt[ci][co] = wf[(cog * 32 + co) * 128 + ci];
  }
  __syncthreads();

  int cog2 = t >> 5;        // 0..7 -> 4 co each
  int pl = (t & 31) * 2;    // px pair
  float a0[4] = {0.f, 0.f, 0.f, 0.f};
  float a1[4] = {0.f, 0.f, 0.f, 0.f};
  for (int ci = 0; ci < 128; ci++) {
    float2 xv = *(const float2*)&xt[ci][pl];
    float4 wv = *(const float4*)&wt[ci][cog2 * 4];
    a0[0] = fmaf(xv.x, wv.x, a0[0]); a1[0] = fmaf(xv.y, wv.x, a1[0]);
    a0[1] = fmaf(xv.x, wv.y, a0[1]); a1[1] = fmaf(xv.y, wv.y, a1[1]);
    a0[2] = fmaf(xv.x, wv.z, a0[2]); a1[2] = fmaf(xv.y, wv.z, a1[2]);
    a0[3] = fmaf(xv.x, wv.w, a0[3]); a1[3] = fmaf(xv.y, wv.w, a1[3]);
  }
#pragma unroll
  for (int j = 0; j < 4; j++) {
    int co = cog * 32 + cog2 * 4 + j;
    float bv = bias[co];
    float v0 = a0[j] + bv, v1 = a1[j] + bv;
    float* dst;
    if (co < 64) { dst = qbuf; v0 *= QSCALE; v1 *= QSCALE; }
    else if (co < 128) dst = kbuf;
    else dst = vbuf;
    float2 pk; pk.x = v0; pk.y = v1;
    *(float2*)(dst + ((size_t)b * 64 + (co & 63)) * NP + p0 + pl) = pk;
  }
}

// ---------------------------------------------------------------------------
// Kernel 2: attention. Same structure as R9, PLUS inline-asm register pinning
// of q (and M) so LLVM cannot rematerialize the loop-invariant q loads
// (R9 post-mortem: VGPR=60 with ~2.7x VALU instruction bloat from remat).
// ---------------------------------------------------------------------------
__global__ __launch_bounds__(256, 4) void attn_kernel(
    const float* __restrict__ qbuf, const float* __restrict__ kbuf, const float* __restrict__ vbuf,
    const float* __restrict__ krh, const float* __restrict__ krw,
    ushort* __restrict__ apb)
{
  __shared__ float bw2[2][NP];
  __shared__ float bhT[2][32][32];
  __shared__ float qsT[2][32][8];
  __shared__ float krhs[64][8];
  __shared__ float krws[64][8];
  __shared__ int smax[3];

  int t = threadIdx.x;
  int cp = blockIdx.x, h = blockIdx.y, b = blockIdx.z;
  int C0 = cp * 2;
  const float* qbase = qbuf + ((size_t)b * 64 + h * 8) * NP;
  const float* kbase = kbuf + ((size_t)b * 64 + h * 8) * NP;
  const float* vbase = vbuf + ((size_t)b * 64 + h * 8) * NP;

  if (t < 3) smax[t] = (t == 0) ? 0 : fenc(-3.0e38f);

  for (int idx = t; idx < 63 * 8; idx += 256) {
    krhs[idx >> 3][idx & 7] = krh[idx];
    krws[idx >> 3][idx & 7] = krw[idx];
  }
  for (int idx = t; idx < 512; idx += 256) {
    int cs = idx >> 8, d = (idx >> 5) & 7, r = idx & 31;
    qsT[cs][r][d] = qbase[(size_t)d * NP + r * 32 + (C0 + cs)];
  }
  float kn2 = 0.f;
#pragma unroll
  for (int rr = 0; rr < 4; rr++) {
    int m = rr * 256 + t;
    const float4* ks = (const float4*)(kbase + (size_t)m * 8);
    float4 a = ks[0], c = ks[1];
    float nn = a.x * a.x + a.y * a.y + a.z * a.z + a.w * a.w +
               c.x * c.x + c.y * c.y + c.z * c.z + c.w * c.w;
    kn2 = fmaxf(kn2, nn);
  }
  __syncthreads();
  atomicMax(&smax[0], __float_as_int(kn2));

  float bwm = -3.0e38f;
  for (int idx = t; idx < 2048; idx += 256) {
    int cs = idx >> 10, m = idx & 1023;
    int rg = m >> 5, j2 = m & 31;
    float s = dot8(qsT[cs][rg], krws[j2 - rg + 31]) * LOG2E;
    bw2[cs][m] = s;
    bwm = fmaxf(bwm, s);
  }
  float bhm = -3.0e38f;
  for (int idx = t; idx < 2048; idx += 256) {
    int cs = idx >> 10, r = idx & 1023;
    int i = r >> 5, J = r & 31;
    float s = dot8(qsT[cs][i], krhs[J - (C0 + cs) + 31]) * LOG2E;
    bhT[cs][i][J] = s;
    bhm = fmaxf(bhm, s);
  }
  atomicMax(&smax[1], fenc(bwm));
  atomicMax(&smax[2], fenc(bhm));
  __syncthreads();

  float kmaxn = sqrtf(__int_as_float(smax[0]));
  float bmax = fdec(smax[1]) + fdec(smax[2]);

  int Csub = t >> 7, rowg = (t >> 5) & 3, seg = t & 31;
  int C = C0 + Csub;
  const float* bwX = bw2[Csub];
  const float* qrowbase = qbase + (size_t)C * 256 + rowg * 64;

#pragma unroll 1
  for (int ph = 0; ph < 2; ph++) {
    const float* qrow = qrowbase + ph * 32;
    float q[4][8], M[4], l[4], O[4][8];
#pragma unroll
    for (int r = 0; r < 4; r++) {
      float nn = 0.f;
#pragma unroll
      for (int d = 0; d < 8; d++) {
        float v = qrow[r * 8 + d] * LOG2E;
        q[r][d] = v;
        nn = fmaf(v, v, nn);
      }
      M[r] = sqrtf(nn) * kmaxn + bmax;
      l[r] = 0.f;
#pragma unroll
      for (int d = 0; d < 8; d++) O[r][d] = 0.f;
    }
    // Pin q/M into VGPRs: empty asm outputs are opaque to LLVM's
    // rematerializer, preventing per-iteration reloads from global.
#pragma unroll
    for (int r = 0; r < 4; r++) {
      asm volatile("" : "+v"(q[r][0]), "+v"(q[r][1]), "+v"(q[r][2]), "+v"(q[r][3]),
                        "+v"(q[r][4]), "+v"(q[r][5]), "+v"(q[r][6]), "+v"(q[r][7]));
    }
    asm volatile("" : "+v"(M[0]), "+v"(M[1]), "+v"(M[2]), "+v"(M[3]));

    for (int i = 0; i < 32; ++i) {
      int m = i * 32 + seg;
      const float4* kp = (const float4*)(kbase + (size_t)m * 8);
      float4 ka = kp[0], kc = kp[1];
      float kk[8] = {ka.x, ka.y, ka.z, ka.w, kc.x, kc.y, kc.z, kc.w};
      const float4* vp = (const float4*)(vbase + (size_t)m * 8);
      float4 va = vp[0], vc = vp[1];
      float vv[8] = {va.x, va.y, va.z, va.w, vc.x, vc.y, vc.z, vc.w};
      float bwv = bwX[m];
      float4 bh4 = *(const float4*)&bhT[Csub][i][rowg * 8 + ph * 4];
      float cr[4] = {bh4.x, bh4.y, bh4.z, bh4.w};
#pragma unroll
      for (int r = 0; r < 4; ++r) {
        float s = bwv + (cr[r] - M[r]);
        s = fmaf(q[r][0], kk[0], s); s = fmaf(q[r][1], kk[1], s);
        s = fmaf(q[r][2], kk[2], s); s = fmaf(q[r][3], kk[3], s);
        s = fmaf(q[r][4], kk[4], s); s = fmaf(q[r][5], kk[5], s);
        s = fmaf(q[r][6], kk[6], s); s = fmaf(q[r][7], kk[7], s);
        float p = EXP2F(s);
        l[r] += p;
#pragma unroll
        for (int d = 0; d < 8; ++d) O[r][d] = fmaf(p, vv[d], O[r][d]);
      }
    }

#pragma unroll
    for (int off = 1; off < 32; off <<= 1) {
#pragma unroll
      for (int r = 0; r < 4; r++) {
        l[r] += __shfl_xor(l[r], off);
#pragma unroll
        for (int d = 0; d < 8; d++) O[r][d] += __shfl_xor(O[r][d], off);
      }
    }
    if (seg == 0) {
#pragma unroll
      for (int r = 0; r < 4; r++) {
        float inv = 1.f / l[r];
        int n = C * 32 + rowg * 8 + ph * 4 + r;
        int yy = (n >> 5) + 1, xx = (n & 31) + 1;
        ushort u[8];
#pragma unroll
        for (int d = 0; d < 8; d++) u[d] = f2b(O[r][d] * inv);
        uint4 pk;
        pk.x = (uint)u[0] | ((uint)u[1] << 16);
        pk.y = (uint)u[2] | ((uint)u[3] << 16);
        pk.z = (uint)u[4] | ((uint)u[5] << 16);
        pk.w = (uint)u[6] | ((uint)u[7] << 16);
        *(uint4*)(apb + ((size_t)(b * 34 + yy) * 34 + xx) * 64 + h * 8) = pk;
      }
    }
  }
}

// ---------------------------------------------------------------------------
// Kernel 3: conv3x3 as bf16 MFMA implicit GEMM (unchanged from R9).
// ---------------------------------------------------------------------------
template <int CINT>
__global__ __launch_bounds__(256) void conv_mfma_kernel(
    const ushort* __restrict__ xp, const ushort* __restrict__ wp,
    const float* __restrict__ bias, void* __restrict__ out,
    int co_base, const int* __restrict__ flag)
{
  int pt = blockIdx.x;            // px tile: 16 px
  int b  = blockIdx.y;
  int lane = threadIdx.x & 63;
  int w = threadIdx.x >> 6;       // wave -> co group (16 co)
  int n = lane & 15;              // A: m (co); B: n (px); shared index
  int kg = lane >> 4;             // k-group (8 ci each)
  int p0 = pt * 16;
  int y = p0 >> 5, x0 = p0 & 31;

  const ushort* abase = wp + (size_t)(w * 16 + n) * CINT + kg * 8;
  const ushort* bbase = xp + ((size_t)(b * 34 + y) * 34 + x0 + n) * CINT + kg * 8;

  f32x4 acc = {0.f, 0.f, 0.f, 0.f};
#pragma unroll
  for (int c = 0; c < CINT / 32; c++) {
    int ci0 = c * 32;
#pragma unroll
    for (int ky = 0; ky < 3; ky++) {
#pragma unroll
      for (int kx = 0; kx < 3; kx++) {
        bf16x8 A = *(const bf16x8*)(abase + (size_t)(ky * 3 + kx) * 64 * CINT + ci0);
        bf16x8 B = *(const bf16x8*)(bbase + (size_t)(ky * 34 + kx) * CINT + ci0);
        acc = __builtin_amdgcn_mfma_f32_16x16x32_bf16(A, B, acc, 0, 0, 0);
      }
    }
  }

  int f32o = *flag;
#pragma unroll
  for (int r = 0; r < 4; r++) {
    int co = w * 16 + kg * 4 + r;        // D row = (lane>>4)*4 + r
    float v = acc[r] + bias[co];
    size_t eoff = ((size_t)b * 128 + co_base + co) * 1024 + p0 + n;   // D col = n
    if (f32o) ((float*)out)[eoff] = v;
    else ((bf16*)out)[eoff] = __float2bfloat16(v);
  }
}

// ---------------------------------------------------------------------------
extern "C" void kernel_launch(void* const* d_in, const int* in_sizes, int n_in,
                              void* d_out, int out_size, void* d_ws, size_t ws_size,
                              hipStream_t stream) {
  float* ws = (float*)d_ws;
  float*  wqkvf = ws + OFF_WQKV;
  float*  bgf   = ws + OFF_BG;
  float*  bqkvf = ws + OFF_BQKV;
  float*  bof   = ws + OFF_BO;
  float*  krhf  = ws + OFF_KRH;
  float*  krwf  = ws + OFF_KRW;
  float*  qbuf  = ws + OFF_QBUF;
  float*  kbuf  = ws + OFF_KBUF;
  float*  vbuf  = ws + OFF_VBUF;
  ushort* xpb   = (ushort*)(ws + OFF_XPB);
  ushort* apb   = (ushort*)(ws + OFF_APB);
  ushort* wgb   = (ushort*)(ws + OFF_WGB);
  ushort* wob   = (ushort*)(ws + OFF_WOB);
  int*    flag  = (int*)(ws + OFF_FLAG);

  cvt_kernel<<<512, 256, 0, stream>>>(d_in[0], d_in[1], d_in[2], d_in[3], d_in[4],
                                      d_in[5], d_in[6], d_in[7], d_in[8], ws, flag);
  xpose_kernel<<<128, 256, 0, stream>>>(d_in[0], xpb, flag);
  qkv_kernel<<<dim3(8, 16, 6), 256, 0, stream>>>(d_in[0], wqkvf, bqkvf, qbuf, kbuf, vbuf, flag);
  conv_mfma_kernel<128><<<dim3(64, 8), 256, 0, stream>>>(xpb, wgb, bgf, d_out, 0, flag);
  attn_kernel<<<dim3(16, 8, 8), 256, 0, stream>>>(qbuf, kbuf, vbuf, krhf, krwf, apb);
  conv_mfma_kernel<64><<<dim3(64, 8), 256, 0, stream>>>(apb, wob, bof, d_out, 64, flag);
}